// Round 5
// baseline (390.715 us; speedup 1.0000x reference)
//
#include <hip/hip_runtime.h>
#include <hip/hip_bf16.h>
#include <stdint.h>

#define NH 16
#define DH 64
#define BATCH 2
#define SEQ 2048
#define DMODEL 1024

typedef __attribute__((ext_vector_type(8))) short short8;
typedef __attribute__((ext_vector_type(4))) float f32x4;

#define MFMA16(a, b, c) __builtin_amdgcn_mfma_f32_16x16x32_bf16(a, b, c, 0, 0, 0)

__device__ inline unsigned short f2bf(float f) {
    union { float f; unsigned u; } v; v.f = f;
    unsigned r = v.u + 0x7fff + ((v.u >> 16) & 1);
    return (unsigned short)(r >> 16);
}

__device__ inline void gload_lds16(const unsigned short* g, unsigned short* l) {
    __builtin_amdgcn_global_load_lds((const __attribute__((address_space(1))) void*)g,
                                     (__attribute__((address_space(3))) void*)l, 16, 0, 0);
}

// ---------- fp32 -> bf16 convert (8 elems/thread) ----------
__global__ void k_cvt(const float* __restrict__ in, unsigned short* __restrict__ out) {
    size_t i = ((size_t)blockIdx.x * 256 + threadIdx.x) * 8;
    f32x4 a = *(const f32x4*)(in + i);
    f32x4 b = *(const f32x4*)(in + i + 4);
    short8 o;
    o[0] = (short)f2bf(a[0]); o[1] = (short)f2bf(a[1]);
    o[2] = (short)f2bf(a[2]); o[3] = (short)f2bf(a[3]);
    o[4] = (short)f2bf(b[0]); o[5] = (short)f2bf(b[1]);
    o[6] = (short)f2bf(b[2]); o[7] = (short)f2bf(b[3]);
    *(short8*)(out + i) = o;
}

// ---------- weight transpose [K][N] fp32 -> [N][K] bf16 ----------
__global__ void k_transpose_w(const float* __restrict__ w, unsigned short* __restrict__ out) {
    __shared__ float tile[32][33];
    int k0 = blockIdx.x * 32, n0 = blockIdx.y * 32;
    int tx = threadIdx.x, ty = threadIdx.y;  // 32 x 8
    #pragma unroll
    for (int j = 0; j < 32; j += 8)
        tile[ty + j][tx] = w[(size_t)(k0 + ty + j) * DMODEL + n0 + tx];
    __syncthreads();
    #pragma unroll
    for (int j = 0; j < 32; j += 8)
        out[(size_t)(n0 + ty + j) * DMODEL + k0 + tx] = f2bf(tile[tx][ty + j]);
}

// ---------- V transpose per head: [bh][2048][64] -> [bh][64][2048] bf16 ----------
__global__ __launch_bounds__(256) void k_transpose_v(const unsigned short* __restrict__ v,
                                                     unsigned short* __restrict__ vt) {
    __shared__ __align__(16) unsigned short tile[64][72];
    int bh = blockIdx.y, st = blockIdx.x;
    const unsigned short* src = v + ((size_t)bh * SEQ + st * 64) * DH;
    int r = threadIdx.x >> 2, c = (threadIdx.x & 3) * 16;
    *(short8*)&tile[r][c]     = *(const short8*)&src[r * DH + c];
    *(short8*)&tile[r][c + 8] = *(const short8*)&src[r * DH + c + 8];
    __syncthreads();
    int d = r, sb = c;
    short8 o0, o1;
    #pragma unroll
    for (int j = 0; j < 8; ++j) { o0[j] = (short)tile[sb + j][d]; o1[j] = (short)tile[sb + 8 + j][d]; }
    unsigned short* dst = vt + ((size_t)bh * DH + d) * SEQ + st * 64 + sb;
    *(short8*)dst = o0;
    *(short8*)(dst + 8) = o1;
}

// ---------- GEMM core: 128x128 tile, BK=32, 4 waves (2x2), m97 structure ----------
#define GEMM_BODY(A_, Bt_)                                                              \
    __shared__ __align__(16) unsigned short As[128 * 32];                               \
    __shared__ __align__(16) unsigned short Bs[128 * 32];                               \
    const int tid = threadIdx.x;                                                        \
    const int lane = tid & 63, wave = tid >> 6;                                         \
    const int wr = wave >> 1, wc = wave & 1;                                            \
    const int row0 = blockIdx.y * 128, col0 = blockIdx.x * 128;                         \
    const int frow = lane & 15, fk = (lane >> 4) * 8;                                   \
    f32x4 acc[4][4] = {};                                                               \
    const int lr = tid >> 2;                                                            \
    const int lc = (tid & 3) * 8;                                                       \
    const unsigned short* ga0 = A_ + (size_t)(row0 + lr) * 1024 + lc;                   \
    const unsigned short* gb0 = Bt_ + (size_t)(col0 + lr) * 1024 + lc;                  \
    for (int kt = 0; kt < 1024; kt += 32) {                                             \
        gload_lds16(ga0 + kt, As + wave * 512);                                         \
        gload_lds16(ga0 + 64 * 1024 + kt, As + 2048 + wave * 512);                      \
        gload_lds16(gb0 + kt, Bs + wave * 512);                                         \
        gload_lds16(gb0 + 64 * 1024 + kt, Bs + 2048 + wave * 512);                      \
        __syncthreads();                                                                \
        short8 af[4], bf[4];                                                            \
        _Pragma("unroll")                                                               \
        for (int m = 0; m < 4; ++m)                                                     \
            af[m] = *(const short8*)&As[(wr * 64 + m * 16 + frow) * 32 + fk];           \
        _Pragma("unroll")                                                               \
        for (int n = 0; n < 4; ++n)                                                     \
            bf[n] = *(const short8*)&Bs[(wc * 64 + n * 16 + frow) * 32 + fk];           \
        _Pragma("unroll")                                                               \
        for (int m = 0; m < 4; ++m)                                                     \
            _Pragma("unroll")                                                           \
            for (int n = 0; n < 4; ++n)                                                 \
                acc[m][n] = MFMA16(af[m], bf[n], acc[m][n]);                            \
        __syncthreads();                                                                \
    }

// QKV projection GEMM: N=3072 (q|k|v), scatters to [B,H,S,Dh] bf16, Q scaled by 1/8
__global__ __launch_bounds__(256) void k_gemm_qkv(
    const unsigned short* __restrict__ A, const unsigned short* __restrict__ Bt,
    const float* __restrict__ bq, const float* __restrict__ bk, const float* __restrict__ bv,
    unsigned short* __restrict__ qo, unsigned short* __restrict__ ko,
    unsigned short* __restrict__ vo)
{
    GEMM_BODY(A, Bt)
    const int p = col0 >> 10;  // 0=q 1=k 2=v, uniform per block
    const float* bias = (p == 0) ? bq : ((p == 1) ? bk : bv);
    unsigned short* dst = (p == 0) ? qo : ((p == 1) ? ko : vo);
    const float scl = (p == 0) ? 0.125f : 1.0f;
    #pragma unroll
    for (int m = 0; m < 4; ++m) {
        #pragma unroll
        for (int n = 0; n < 4; ++n) {
            int gcol = col0 + wc * 64 + n * 16 + frow;
            int hn = gcol & 1023;
            int h = hn >> 6, d = hn & 63;
            #pragma unroll
            for (int i = 0; i < 4; ++i) {
                int grow = row0 + wr * 64 + m * 16 + (lane >> 4) * 4 + i;
                int b = grow >> 11, s = grow & 2047;
                float v = (acc[m][n][i] + bias[hn]) * scl;
                dst[((size_t)(b * NH + h) * SEQ + s) * DH + d] = f2bf(v);
            }
        }
    }
}

// Output projection GEMM: fp32 out + bias
__global__ __launch_bounds__(256) void k_gemm_out(
    const unsigned short* __restrict__ A, const unsigned short* __restrict__ Bt,
    const float* __restrict__ bo, float* __restrict__ out)
{
    GEMM_BODY(A, Bt)
    #pragma unroll
    for (int m = 0; m < 4; ++m) {
        #pragma unroll
        for (int n = 0; n < 4; ++n) {
            int gcol = col0 + wc * 64 + n * 16 + frow;
            #pragma unroll
            for (int i = 0; i < 4; ++i) {
                int grow = row0 + wr * 64 + m * 16 + (lane >> 4) * 4 + i;
                out[(size_t)grow * DMODEL + gcol] = acc[m][n][i] + bo[gcol];
            }
        }
    }
}

// ---------- causal flash attention, barrier-free ----------
// Q,K: [B*H][S][DH] bf16 (Q pre-scaled). VT: [B*H][DH][S] bf16. O: [B][S][H*DH] bf16.
// K/V fragments read straight from global (L2-resident with XCD swizzle).
__global__ __launch_bounds__(256) void k_attn(
    const unsigned short* __restrict__ Q, const unsigned short* __restrict__ K,
    const unsigned short* __restrict__ VT, unsigned short* __restrict__ O)
{
    __shared__ __align__(16) unsigned short Ps[4][16 * 72];
    const int tid = threadIdx.x, lane = tid & 63, wave = tid >> 6;
    // XCD-aware swizzle: physical p -> logical L so 4 heads share each XCD's L2
    const int p = blockIdx.x;
    const int L = ((p & 7) << 7) | (p >> 3);
    const int bh = L >> 5, qt = L & 31;
    const int q0 = qt * 64;
    const unsigned short* Qb = Q + (size_t)bh * SEQ * DH;
    const unsigned short* Kb = K + (size_t)bh * SEQ * DH;
    const unsigned short* Vb = VT + (size_t)bh * SEQ * DH;  // [64][2048]
    const int frow = lane & 15, fk = (lane >> 4) * 8;

    short8 qf[2];
    #pragma unroll
    for (int t = 0; t < 2; ++t)
        qf[t] = *(const short8*)&Qb[(size_t)(q0 + wave * 16 + frow) * DH + t * 32 + fk];

    f32x4 oacc[4] = {};
    float mrow[4], lrow[4];
    #pragma unroll
    for (int i = 0; i < 4; ++i) { mrow[i] = -INFINITY; lrow[i] = 0.f; }

    for (int kt = 0; kt <= qt; ++kt) {
        const int kv0 = kt * 64;
        // QK^T straight from global K
        f32x4 sc[4];
        #pragma unroll
        for (int n = 0; n < 4; ++n) {
            f32x4 s = {0.f, 0.f, 0.f, 0.f};
            #pragma unroll
            for (int t = 0; t < 2; ++t) {
                short8 kb = *(const short8*)&Kb[(size_t)(kv0 + n * 16 + frow) * DH + t * 32 + fk];
                s = MFMA16(qf[t], kb, s);
            }
            sc[n] = s;
        }
        // prefetch V^T fragments (latency hides under softmax)
        short8 vf[4][2];
        #pragma unroll
        for (int n = 0; n < 4; ++n)
            #pragma unroll
            for (int t = 0; t < 2; ++t)
                vf[n][t] = *(const short8*)&Vb[(size_t)(n * 16 + frow) * SEQ + kv0 + t * 32 + fk];
        if (kt == qt) {  // causal mask on diagonal tile
            #pragma unroll
            for (int n = 0; n < 4; ++n) {
                int col = n * 16 + frow;
                #pragma unroll
                for (int i = 0; i < 4; ++i) {
                    int qrel = wave * 16 + (lane >> 4) * 4 + i;
                    if (col > qrel) sc[n][i] = -INFINITY;
                }
            }
        }
        // online softmax with defer-max (THR=8)
        float mx[4];
        #pragma unroll
        for (int i = 0; i < 4; ++i) {
            float m = fmaxf(fmaxf(sc[0][i], sc[1][i]), fmaxf(sc[2][i], sc[3][i]));
            m = fmaxf(m, __shfl_xor(m, 1));
            m = fmaxf(m, __shfl_xor(m, 2));
            m = fmaxf(m, __shfl_xor(m, 4));
            m = fmaxf(m, __shfl_xor(m, 8));
            mx[i] = m;
        }
        float dm = fmaxf(fmaxf(mx[0] - mrow[0], mx[1] - mrow[1]),
                         fmaxf(mx[2] - mrow[2], mx[3] - mrow[3]));
        if (__any(dm > 8.f)) {
            #pragma unroll
            for (int i = 0; i < 4; ++i) {
                float mnew = fmaxf(mrow[i], mx[i]);
                float scl = __expf(mrow[i] - mnew);
                mrow[i] = mnew;
                lrow[i] *= scl;
                #pragma unroll
                for (int n = 0; n < 4; ++n) oacc[n][i] *= scl;
            }
        }
        #pragma unroll
        for (int i = 0; i < 4; ++i) {
            float rsum = 0.f;
            #pragma unroll
            for (int n = 0; n < 4; ++n) {
                float pv = __expf(sc[n][i] - mrow[i]);
                sc[n][i] = pv;
                rsum += pv;
            }
            rsum += __shfl_xor(rsum, 1);
            rsum += __shfl_xor(rsum, 2);
            rsum += __shfl_xor(rsum, 4);
            rsum += __shfl_xor(rsum, 8);
            lrow[i] += rsum;
        }
        // P -> wave-private LDS (bf16), padded stride 72 (2-way = free)
        #pragma unroll
        for (int n = 0; n < 4; ++n)
            #pragma unroll
            for (int i = 0; i < 4; ++i)
                Ps[wave][((lane >> 4) * 4 + i) * 72 + n * 16 + frow] = f2bf(sc[n][i]);
        short8 pa[2];
        #pragma unroll
        for (int t = 0; t < 2; ++t)
            pa[t] = *(const short8*)&Ps[wave][frow * 72 + t * 32 + fk];
        #pragma unroll
        for (int n = 0; n < 4; ++n)
            #pragma unroll
            for (int t = 0; t < 2; ++t)
                oacc[n] = MFMA16(pa[t], vf[n][t], oacc[n]);
    }
    // epilogue: O[b][s][h*64+d], normalized
    int b = bh >> 4, h = bh & 15;
    #pragma unroll
    for (int n = 0; n < 4; ++n) {
        #pragma unroll
        for (int i = 0; i < 4; ++i) {
            int qrow = q0 + wave * 16 + (lane >> 4) * 4 + i;
            float v = oacc[n][i] / lrow[i];
            O[((size_t)(b * SEQ + qrow)) * DMODEL + h * DH + n * 16 + frow] = f2bf(v);
        }
    }
}

extern "C" void kernel_launch(void* const* d_in, const int* in_sizes, int n_in,
                              void* d_out, int out_size, void* d_ws, size_t ws_size,
                              hipStream_t stream) {
    const float* x  = (const float*)d_in[0];
    const float* wq = (const float*)d_in[1];
    const float* bq = (const float*)d_in[2];
    const float* wk = (const float*)d_in[3];
    const float* bk = (const float*)d_in[4];
    const float* wv = (const float*)d_in[5];
    const float* bv = (const float*)d_in[6];
    const float* wo = (const float*)d_in[7];
    const float* bo = (const float*)d_in[8];
    float* out = (float*)d_out;

    char* w = (char*)d_ws;
    unsigned short* xb    = (unsigned short*)(w);            // 8 MB, freed after qkv GEMM
    unsigned short* vT    = (unsigned short*)(w);            // reuses xb region
    unsigned short* wqkvT = (unsigned short*)(w + 8388608);
    unsigned short* woT   = (unsigned short*)(w + 14680064);
    unsigned short* qarr  = (unsigned short*)(w + 16777216);
    unsigned short* karr  = (unsigned short*)(w + 25165824);
    unsigned short* varr  = (unsigned short*)(w + 33554432);
    unsigned short* attnb = (unsigned short*)(w + 41943040);

    k_cvt<<<2048, 256, 0, stream>>>(x, xb);
    dim3 tb(32, 8);
    dim3 tg(32, 32);
    k_transpose_w<<<tg, tb, 0, stream>>>(wq, wqkvT);
    k_transpose_w<<<tg, tb, 0, stream>>>(wk, wqkvT + 1024 * 1024);
    k_transpose_w<<<tg, tb, 0, stream>>>(wv, wqkvT + 2 * 1024 * 1024);
    k_transpose_w<<<tg, tb, 0, stream>>>(wo, woT);
    k_gemm_qkv<<<dim3(24, 32), 256, 0, stream>>>(xb, wqkvT, bq, bk, bv, qarr, karr, varr);
    k_transpose_v<<<dim3(32, 32), 256, 0, stream>>>(varr, vT);
    k_attn<<<dim3(1024), 256, 0, stream>>>(qarr, karr, vT, attnb);
    k_gemm_out<<<dim3(8, 32), 256, 0, stream>>>(attnb, woT, bo, out);
}

// Round 6
// 230.129 us; speedup vs baseline: 1.6978x; 1.6978x over previous
//
#include <hip/hip_runtime.h>
#include <hip/hip_bf16.h>
#include <stdint.h>

#define NH 16
#define DH 64
#define BATCH 2
#define SEQ 2048
#define DMODEL 1024

typedef __attribute__((ext_vector_type(8))) short short8;
typedef __attribute__((ext_vector_type(4))) float f32x4;

#define MFMA16(a, b, c) __builtin_amdgcn_mfma_f32_16x16x32_bf16(a, b, c, 0, 0, 0)

__device__ inline unsigned short f2bf(float f) {
    union { float f; unsigned u; } v; v.f = f;
    unsigned r = v.u + 0x7fff + ((v.u >> 16) & 1);
    return (unsigned short)(r >> 16);
}

__device__ inline void gload_lds16(const unsigned short* g, unsigned short* l) {
    __builtin_amdgcn_global_load_lds((const __attribute__((address_space(1))) void*)g,
                                     (__attribute__((address_space(3))) void*)l, 16, 0, 0);
}

// ---------- fp32 -> bf16 convert (8 elems/thread) ----------
__global__ void k_cvt(const float* __restrict__ in, unsigned short* __restrict__ out) {
    size_t i = ((size_t)blockIdx.x * 256 + threadIdx.x) * 8;
    f32x4 a = *(const f32x4*)(in + i);
    f32x4 b = *(const f32x4*)(in + i + 4);
    short8 o;
    o[0] = (short)f2bf(a[0]); o[1] = (short)f2bf(a[1]);
    o[2] = (short)f2bf(a[2]); o[3] = (short)f2bf(a[3]);
    o[4] = (short)f2bf(b[0]); o[5] = (short)f2bf(b[1]);
    o[6] = (short)f2bf(b[2]); o[7] = (short)f2bf(b[3]);
    *(short8*)(out + i) = o;
}

// ---------- weight transpose [K][N] fp32 -> [N][K] bf16 ----------
__global__ void k_transpose_w(const float* __restrict__ w, unsigned short* __restrict__ out) {
    __shared__ float tile[32][33];
    int k0 = blockIdx.x * 32, n0 = blockIdx.y * 32;
    int tx = threadIdx.x, ty = threadIdx.y;  // 32 x 8
    #pragma unroll
    for (int j = 0; j < 32; j += 8)
        tile[ty + j][tx] = w[(size_t)(k0 + ty + j) * DMODEL + n0 + tx];
    __syncthreads();
    #pragma unroll
    for (int j = 0; j < 32; j += 8)
        out[(size_t)(n0 + ty + j) * DMODEL + k0 + tx] = f2bf(tile[tx][ty + j]);
}

// ---------- V transpose per head: [bh][2048][64] -> [bh][64][2048] bf16 ----------
__global__ __launch_bounds__(256) void k_transpose_v(const unsigned short* __restrict__ v,
                                                     unsigned short* __restrict__ vt) {
    __shared__ __align__(16) unsigned short tile[64][72];
    int bh = blockIdx.y, st = blockIdx.x;
    const unsigned short* src = v + ((size_t)bh * SEQ + st * 64) * DH;
    int r = threadIdx.x >> 2, c = (threadIdx.x & 3) * 16;
    *(short8*)&tile[r][c]     = *(const short8*)&src[r * DH + c];
    *(short8*)&tile[r][c + 8] = *(const short8*)&src[r * DH + c + 8];
    __syncthreads();
    int d = r, sb = c;
    short8 o0, o1;
    #pragma unroll
    for (int j = 0; j < 8; ++j) { o0[j] = (short)tile[sb + j][d]; o1[j] = (short)tile[sb + 8 + j][d]; }
    unsigned short* dst = vt + ((size_t)bh * DH + d) * SEQ + st * 64 + sb;
    *(short8*)dst = o0;
    *(short8*)(dst + 8) = o1;
}

// ---------- GEMM core: 128x128 tile, BK=32, 4 waves (2x2), m97 structure ----------
#define GEMM_BODY(A_, Bt_)                                                              \
    __shared__ __align__(16) unsigned short As[128 * 32];                               \
    __shared__ __align__(16) unsigned short Bs[128 * 32];                               \
    const int tid = threadIdx.x;                                                        \
    const int lane = tid & 63, wave = tid >> 6;                                         \
    const int wr = wave >> 1, wc = wave & 1;                                            \
    const int row0 = blockIdx.y * 128, col0 = blockIdx.x * 128;                         \
    const int frow = lane & 15, fk = (lane >> 4) * 8;                                   \
    f32x4 acc[4][4] = {};                                                               \
    const int lr = tid >> 2;                                                            \
    const int lc = (tid & 3) * 8;                                                       \
    const unsigned short* ga0 = A_ + (size_t)(row0 + lr) * 1024 + lc;                   \
    const unsigned short* gb0 = Bt_ + (size_t)(col0 + lr) * 1024 + lc;                  \
    for (int kt = 0; kt < 1024; kt += 32) {                                             \
        gload_lds16(ga0 + kt, As + wave * 512);                                         \
        gload_lds16(ga0 + 64 * 1024 + kt, As + 2048 + wave * 512);                      \
        gload_lds16(gb0 + kt, Bs + wave * 512);                                         \
        gload_lds16(gb0 + 64 * 1024 + kt, Bs + 2048 + wave * 512);                      \
        __syncthreads();                                                                \
        short8 af[4], bf[4];                                                            \
        _Pragma("unroll")                                                               \
        for (int m = 0; m < 4; ++m)                                                     \
            af[m] = *(const short8*)&As[(wr * 64 + m * 16 + frow) * 32 + fk];           \
        _Pragma("unroll")                                                               \
        for (int n = 0; n < 4; ++n)                                                     \
            bf[n] = *(const short8*)&Bs[(wc * 64 + n * 16 + frow) * 32 + fk];           \
        _Pragma("unroll")                                                               \
        for (int m = 0; m < 4; ++m)                                                     \
            _Pragma("unroll")                                                           \
            for (int n = 0; n < 4; ++n)                                                 \
                acc[m][n] = MFMA16(af[m], bf[n], acc[m][n]);                            \
        __syncthreads();                                                                \
    }

// QKV projection GEMM: N=3072 (q|k|v), scatters to [B,H,S,Dh] bf16, Q scaled by 1/8
__global__ __launch_bounds__(256) void k_gemm_qkv(
    const unsigned short* __restrict__ A, const unsigned short* __restrict__ Bt,
    const float* __restrict__ bq, const float* __restrict__ bk, const float* __restrict__ bv,
    unsigned short* __restrict__ qo, unsigned short* __restrict__ ko,
    unsigned short* __restrict__ vo)
{
    GEMM_BODY(A, Bt)
    const int p = col0 >> 10;  // 0=q 1=k 2=v, uniform per block
    const float* bias = (p == 0) ? bq : ((p == 1) ? bk : bv);
    unsigned short* dst = (p == 0) ? qo : ((p == 1) ? ko : vo);
    const float scl = (p == 0) ? 0.125f : 1.0f;
    #pragma unroll
    for (int m = 0; m < 4; ++m) {
        #pragma unroll
        for (int n = 0; n < 4; ++n) {
            int gcol = col0 + wc * 64 + n * 16 + frow;
            int hn = gcol & 1023;
            int h = hn >> 6, d = hn & 63;
            #pragma unroll
            for (int i = 0; i < 4; ++i) {
                int grow = row0 + wr * 64 + m * 16 + (lane >> 4) * 4 + i;
                int b = grow >> 11, s = grow & 2047;
                float v = (acc[m][n][i] + bias[hn]) * scl;
                dst[((size_t)(b * NH + h) * SEQ + s) * DH + d] = f2bf(v);
            }
        }
    }
}

// Output projection GEMM: fp32 out + bias
__global__ __launch_bounds__(256) void k_gemm_out(
    const unsigned short* __restrict__ A, const unsigned short* __restrict__ Bt,
    const float* __restrict__ bo, float* __restrict__ out)
{
    GEMM_BODY(A, Bt)
    #pragma unroll
    for (int m = 0; m < 4; ++m) {
        #pragma unroll
        for (int n = 0; n < 4; ++n) {
            int gcol = col0 + wc * 64 + n * 16 + frow;
            #pragma unroll
            for (int i = 0; i < 4; ++i) {
                int grow = row0 + wr * 64 + m * 16 + (lane >> 4) * 4 + i;
                out[(size_t)grow * DMODEL + gcol] = acc[m][n][i] + bo[gcol];
            }
        }
    }
}

// ---------- causal flash attention: LDS-staged, double-buffered, counted vmcnt ----------
// Q,K: [B*H][S][DH] bf16 (Q pre-scaled). VT: [B*H][DH][S] bf16. O: [B][S][H*DH] bf16.
// K/V^T tiles staged via global_load_lds with pre-swizzled source (T2, rule #21):
//   LDS byte o holds element (row=o>>7, colb=(o&127)^((row&7)<<4)) -> ds_read_b128 2-way free.
// 512 blocks: block handles q-tile pair {31-p, p} => uniform 33 tiles (causal balance).
__global__ __launch_bounds__(256) void k_attn(
    const unsigned short* __restrict__ Q, const unsigned short* __restrict__ K,
    const unsigned short* __restrict__ VT, unsigned short* __restrict__ O)
{
    __shared__ __align__(16) unsigned short Ks[2][64 * 64];
    __shared__ __align__(16) unsigned short Vs[2][64 * 64];
    __shared__ __align__(16) unsigned short Ps[4][16 * 72];
    const int tid = threadIdx.x, lane = tid & 63, wave = tid >> 6;
    // XCD swizzle: 64 consecutive logical blocks (4 heads) per XCD -> 2MB KV in 4MB L2
    const int p = blockIdx.x;
    const int L = ((p & 7) << 6) | (p >> 3);
    const int bh = L >> 4, pr = L & 15;
    const unsigned short* Qb = Q + (size_t)bh * SEQ * DH;
    const unsigned short* Kb = K + (size_t)bh * SEQ * DH;
    const unsigned short* Vb = VT + (size_t)bh * SEQ * DH;  // [64][2048]
    const int frow = lane & 15, fk = (lane >> 4) * 8;
    // staging geometry: lane l writes LDS bytes base+l*16; row = 8*wave_sub + (l>>3)
    const int srow = lane >> 3;
    const int scol = ((lane & 7) ^ srow) << 3;  // inverse-swizzled source col (elements)
    const int bb = bh >> 4, hh = bh & 15;

    for (int rep = 0; rep < 2; ++rep) {
        const int qt = rep ? pr : 31 - pr;  // long tile first
        const int q0 = qt * 64;
        short8 qf[2];
        #pragma unroll
        for (int t = 0; t < 2; ++t)
            qf[t] = *(const short8*)&Qb[(size_t)(q0 + wave * 16 + frow) * DH + t * 32 + fk];
        f32x4 oacc[4] = {};
        float mrow[4], lrow[4];
        #pragma unroll
        for (int i = 0; i < 4; ++i) { mrow[i] = -INFINITY; lrow[i] = 0.f; }

        auto stage = [&](int b, int kv0) {  // 4 gload_lds per thread
            #pragma unroll
            for (int rd = 0; rd < 2; ++rd) {
                int row = rd * 32 + wave * 8 + srow;
                gload_lds16(Kb + (size_t)(kv0 + row) * DH + scol,
                            &Ks[b][(rd * 32 + wave * 8) * 64]);
                gload_lds16(Vb + (size_t)row * SEQ + kv0 + scol,
                            &Vs[b][(rd * 32 + wave * 8) * 64]);
            }
        };

        auto compute = [&](int cb_, bool diag) {
            const char* kbase = (const char*)&Ks[cb_][0];
            const char* vbase = (const char*)&Vs[cb_][0];
            const int sw = (frow & 7) << 4;
            // QK^T from swizzled LDS
            f32x4 sc[4];
            #pragma unroll
            for (int n = 0; n < 4; ++n) {
                f32x4 s = {0.f, 0.f, 0.f, 0.f};
                #pragma unroll
                for (int t = 0; t < 2; ++t) {
                    int cbt = (t * 32 + fk) * 2;
                    short8 kb = *(const short8*)(kbase + (n * 16 + frow) * 128 + (cbt ^ sw));
                    s = MFMA16(qf[t], kb, s);
                }
                sc[n] = s;
            }
            if (diag) {  // causal mask on diagonal tile
                #pragma unroll
                for (int n = 0; n < 4; ++n) {
                    int col = n * 16 + frow;
                    #pragma unroll
                    for (int i = 0; i < 4; ++i) {
                        int qrel = wave * 16 + (lane >> 4) * 4 + i;
                        if (col > qrel) sc[n][i] = -INFINITY;
                    }
                }
            }
            // online softmax with defer-max (THR=8)
            float mx[4];
            #pragma unroll
            for (int i = 0; i < 4; ++i) {
                float m = fmaxf(fmaxf(sc[0][i], sc[1][i]), fmaxf(sc[2][i], sc[3][i]));
                m = fmaxf(m, __shfl_xor(m, 1));
                m = fmaxf(m, __shfl_xor(m, 2));
                m = fmaxf(m, __shfl_xor(m, 4));
                m = fmaxf(m, __shfl_xor(m, 8));
                mx[i] = m;
            }
            float dm = fmaxf(fmaxf(mx[0] - mrow[0], mx[1] - mrow[1]),
                             fmaxf(mx[2] - mrow[2], mx[3] - mrow[3]));
            if (__any(dm > 8.f)) {
                #pragma unroll
                for (int i = 0; i < 4; ++i) {
                    float mnew = fmaxf(mrow[i], mx[i]);
                    float scl = __expf(mrow[i] - mnew);
                    mrow[i] = mnew;
                    lrow[i] *= scl;
                    #pragma unroll
                    for (int n = 0; n < 4; ++n) oacc[n][i] *= scl;
                }
            }
            #pragma unroll
            for (int i = 0; i < 4; ++i) {
                float rsum = 0.f;
                #pragma unroll
                for (int n = 0; n < 4; ++n) {
                    float pv = __expf(sc[n][i] - mrow[i]);
                    sc[n][i] = pv;
                    rsum += pv;
                }
                rsum += __shfl_xor(rsum, 1);
                rsum += __shfl_xor(rsum, 2);
                rsum += __shfl_xor(rsum, 4);
                rsum += __shfl_xor(rsum, 8);
                lrow[i] += rsum;
            }
            // P -> wave-private LDS (stride 72, 2-way free)
            #pragma unroll
            for (int n = 0; n < 4; ++n)
                #pragma unroll
                for (int i = 0; i < 4; ++i)
                    Ps[wave][((lane >> 4) * 4 + i) * 72 + n * 16 + frow] = f2bf(sc[n][i]);
            asm volatile("s_waitcnt lgkmcnt(0)" ::: "memory");
            short8 pa[2];
            #pragma unroll
            for (int t = 0; t < 2; ++t)
                pa[t] = *(const short8*)&Ps[wave][frow * 72 + t * 32 + fk];
            // PV from swizzled LDS V^T
            #pragma unroll
            for (int n = 0; n < 4; ++n)
                #pragma unroll
                for (int t = 0; t < 2; ++t) {
                    int cbt = (t * 32 + fk) * 2;
                    short8 vb2 = *(const short8*)(vbase + (n * 16 + frow) * 128 + (cbt ^ sw));
                    oacc[n] = MFMA16(pa[t], vb2, oacc[n]);
                }
        };

        // pipelined K-loop: stage(kt+1) in flight across barrier, vmcnt(4) not 0
        stage(0, 0);
        int cur = 0;
        for (int kt = 0; kt < qt; ++kt) {
            stage(cur ^ 1, (kt + 1) * 64);
            asm volatile("s_waitcnt vmcnt(4)" ::: "memory");
            __builtin_amdgcn_s_barrier();
            compute(cur, false);
            __builtin_amdgcn_s_barrier();
            cur ^= 1;
        }
        asm volatile("s_waitcnt vmcnt(0)" ::: "memory");
        __builtin_amdgcn_s_barrier();
        compute(cur, true);
        // epilogue: O[b][s][h*64+d], normalized
        #pragma unroll
        for (int n = 0; n < 4; ++n) {
            #pragma unroll
            for (int i = 0; i < 4; ++i) {
                int qrow = q0 + wave * 16 + (lane >> 4) * 4 + i;
                float v = oacc[n][i] / lrow[i];
                O[((size_t)(bb * SEQ + qrow)) * DMODEL + hh * DH + n * 16 + frow] = f2bf(v);
            }
        }
        __builtin_amdgcn_s_barrier();  // all waves done reading bufs before next rep's stage
    }
}

extern "C" void kernel_launch(void* const* d_in, const int* in_sizes, int n_in,
                              void* d_out, int out_size, void* d_ws, size_t ws_size,
                              hipStream_t stream) {
    const float* x  = (const float*)d_in[0];
    const float* wq = (const float*)d_in[1];
    const float* bq = (const float*)d_in[2];
    const float* wk = (const float*)d_in[3];
    const float* bk = (const float*)d_in[4];
    const float* wv = (const float*)d_in[5];
    const float* bv = (const float*)d_in[6];
    const float* wo = (const float*)d_in[7];
    const float* bo = (const float*)d_in[8];
    float* out = (float*)d_out;

    char* w = (char*)d_ws;
    unsigned short* xb    = (unsigned short*)(w);            // 8 MB, freed after qkv GEMM
    unsigned short* vT    = (unsigned short*)(w);            // reuses xb region
    unsigned short* wqkvT = (unsigned short*)(w + 8388608);
    unsigned short* woT   = (unsigned short*)(w + 14680064);
    unsigned short* qarr  = (unsigned short*)(w + 16777216);
    unsigned short* karr  = (unsigned short*)(w + 25165824);
    unsigned short* varr  = (unsigned short*)(w + 33554432);
    unsigned short* attnb = (unsigned short*)(w + 41943040);

    k_cvt<<<2048, 256, 0, stream>>>(x, xb);
    dim3 tb(32, 8);
    dim3 tg(32, 32);
    k_transpose_w<<<tg, tb, 0, stream>>>(wq, wqkvT);
    k_transpose_w<<<tg, tb, 0, stream>>>(wk, wqkvT + 1024 * 1024);
    k_transpose_w<<<tg, tb, 0, stream>>>(wv, wqkvT + 2 * 1024 * 1024);
    k_transpose_w<<<tg, tb, 0, stream>>>(wo, woT);
    k_gemm_qkv<<<dim3(24, 32), 256, 0, stream>>>(xb, wqkvT, bq, bk, bv, qarr, karr, varr);
    k_transpose_v<<<dim3(32, 32), 256, 0, stream>>>(varr, vT);
    k_attn<<<dim3(512), 256, 0, stream>>>(qarr, karr, vT, attnb);
    k_gemm_out<<<dim3(8, 32), 256, 0, stream>>>(attnb, woT, bo, out);
}

// Round 7
// 211.514 us; speedup vs baseline: 1.8472x; 1.0880x over previous
//
#include <hip/hip_runtime.h>
#include <hip/hip_bf16.h>
#include <stdint.h>

#define NH 16
#define DH 64
#define BATCH 2
#define SEQ 2048
#define DMODEL 1024

typedef __attribute__((ext_vector_type(8))) short short8;
typedef __attribute__((ext_vector_type(4))) float f32x4;

#define MFMA16(a, b, c) __builtin_amdgcn_mfma_f32_16x16x32_bf16(a, b, c, 0, 0, 0)

__device__ inline unsigned short f2bf(float f) {
    union { float f; unsigned u; } v; v.f = f;
    unsigned r = v.u + 0x7fff + ((v.u >> 16) & 1);
    return (unsigned short)(r >> 16);
}

__device__ inline void gload_lds16(const unsigned short* g, unsigned short* l) {
    __builtin_amdgcn_global_load_lds((const __attribute__((address_space(1))) void*)g,
                                     (__attribute__((address_space(3))) void*)l, 16, 0, 0);
}

// 16-lane rotate-reduce via DPP row_ror (VALU-speed, replaces ds_swizzle shfl chains).
// Reduction group = 16 consecutive lanes = one DPP row. row_ror:k = ctrl 0x120+k.
__device__ inline float dpp16_max(float v) {
    int t;
    t = __builtin_amdgcn_mov_dpp(__float_as_int(v), 0x121, 0xf, 0xf, false);
    v = fmaxf(v, __int_as_float(t));
    t = __builtin_amdgcn_mov_dpp(__float_as_int(v), 0x122, 0xf, 0xf, false);
    v = fmaxf(v, __int_as_float(t));
    t = __builtin_amdgcn_mov_dpp(__float_as_int(v), 0x124, 0xf, 0xf, false);
    v = fmaxf(v, __int_as_float(t));
    t = __builtin_amdgcn_mov_dpp(__float_as_int(v), 0x128, 0xf, 0xf, false);
    v = fmaxf(v, __int_as_float(t));
    return v;
}
__device__ inline float dpp16_sum(float v) {
    int t;
    t = __builtin_amdgcn_mov_dpp(__float_as_int(v), 0x121, 0xf, 0xf, false);
    v += __int_as_float(t);
    t = __builtin_amdgcn_mov_dpp(__float_as_int(v), 0x122, 0xf, 0xf, false);
    v += __int_as_float(t);
    t = __builtin_amdgcn_mov_dpp(__float_as_int(v), 0x124, 0xf, 0xf, false);
    v += __int_as_float(t);
    t = __builtin_amdgcn_mov_dpp(__float_as_int(v), 0x128, 0xf, 0xf, false);
    v += __int_as_float(t);
    return v;
}

// ---------- fp32 -> bf16 convert (8 elems/thread) ----------
__global__ void k_cvt(const float* __restrict__ in, unsigned short* __restrict__ out) {
    size_t i = ((size_t)blockIdx.x * 256 + threadIdx.x) * 8;
    f32x4 a = *(const f32x4*)(in + i);
    f32x4 b = *(const f32x4*)(in + i + 4);
    short8 o;
    o[0] = (short)f2bf(a[0]); o[1] = (short)f2bf(a[1]);
    o[2] = (short)f2bf(a[2]); o[3] = (short)f2bf(a[3]);
    o[4] = (short)f2bf(b[0]); o[5] = (short)f2bf(b[1]);
    o[6] = (short)f2bf(b[2]); o[7] = (short)f2bf(b[3]);
    *(short8*)(out + i) = o;
}

// ---------- fused weight transpose x4: [K][N] fp32 -> [N][K] bf16 ----------
__global__ void k_transpose_w4(const float* __restrict__ wq, const float* __restrict__ wk,
                               const float* __restrict__ wv, const float* __restrict__ wo,
                               unsigned short* __restrict__ qkvT, unsigned short* __restrict__ oT) {
    __shared__ float tile[32][33];
    const int z = blockIdx.z;
    const float* w = (z == 0) ? wq : (z == 1) ? wk : (z == 2) ? wv : wo;
    unsigned short* out = (z == 3) ? oT : qkvT + (size_t)z * 1024 * 1024;
    int k0 = blockIdx.x * 32, n0 = blockIdx.y * 32;
    int tx = threadIdx.x, ty = threadIdx.y;  // 32 x 8
    #pragma unroll
    for (int j = 0; j < 32; j += 8)
        tile[ty + j][tx] = w[(size_t)(k0 + ty + j) * DMODEL + n0 + tx];
    __syncthreads();
    #pragma unroll
    for (int j = 0; j < 32; j += 8)
        out[(size_t)(n0 + ty + j) * DMODEL + k0 + tx] = f2bf(tile[tx][ty + j]);
}

// ---------- V transpose per head: [bh][2048][64] -> [bh][64][2048] bf16 ----------
__global__ __launch_bounds__(256) void k_transpose_v(const unsigned short* __restrict__ v,
                                                     unsigned short* __restrict__ vt) {
    __shared__ __align__(16) unsigned short tile[64][72];
    int bh = blockIdx.y, st = blockIdx.x;
    const unsigned short* src = v + ((size_t)bh * SEQ + st * 64) * DH;
    int r = threadIdx.x >> 2, c = (threadIdx.x & 3) * 16;
    *(short8*)&tile[r][c]     = *(const short8*)&src[r * DH + c];
    *(short8*)&tile[r][c + 8] = *(const short8*)&src[r * DH + c + 8];
    __syncthreads();
    int d = r, sb = c;
    short8 o0, o1;
    #pragma unroll
    for (int j = 0; j < 8; ++j) { o0[j] = (short)tile[sb + j][d]; o1[j] = (short)tile[sb + 8 + j][d]; }
    unsigned short* dst = vt + ((size_t)bh * DH + d) * SEQ + st * 64 + sb;
    *(short8*)dst = o0;
    *(short8*)(dst + 8) = o1;
}

// ---------- GEMM core: 128x128 tile, BK=32, 4 waves (2x2), m97 structure ----------
#define GEMM_BODY(A_, Bt_)                                                              \
    __shared__ __align__(16) unsigned short As[128 * 32];                               \
    __shared__ __align__(16) unsigned short Bs[128 * 32];                               \
    const int tid = threadIdx.x;                                                        \
    const int lane = tid & 63, wave = tid >> 6;                                         \
    const int wr = wave >> 1, wc = wave & 1;                                            \
    const int row0 = blockIdx.y * 128, col0 = blockIdx.x * 128;                         \
    const int frow = lane & 15, fk = (lane >> 4) * 8;                                   \
    f32x4 acc[4][4] = {};                                                               \
    const int lr = tid >> 2;                                                            \
    const int lc = (tid & 3) * 8;                                                       \
    const unsigned short* ga0 = A_ + (size_t)(row0 + lr) * 1024 + lc;                   \
    const unsigned short* gb0 = Bt_ + (size_t)(col0 + lr) * 1024 + lc;                  \
    for (int kt = 0; kt < 1024; kt += 32) {                                             \
        gload_lds16(ga0 + kt, As + wave * 512);                                         \
        gload_lds16(ga0 + 64 * 1024 + kt, As + 2048 + wave * 512);                      \
        gload_lds16(gb0 + kt, Bs + wave * 512);                                         \
        gload_lds16(gb0 + 64 * 1024 + kt, Bs + 2048 + wave * 512);                      \
        __syncthreads();                                                                \
        short8 af[4], bf[4];                                                            \
        _Pragma("unroll")                                                               \
        for (int m = 0; m < 4; ++m)                                                     \
            af[m] = *(const short8*)&As[(wr * 64 + m * 16 + frow) * 32 + fk];           \
        _Pragma("unroll")                                                               \
        for (int n = 0; n < 4; ++n)                                                     \
            bf[n] = *(const short8*)&Bs[(wc * 64 + n * 16 + frow) * 32 + fk];           \
        _Pragma("unroll")                                                               \
        for (int m = 0; m < 4; ++m)                                                     \
            _Pragma("unroll")                                                           \
            for (int n = 0; n < 4; ++n)                                                 \
                acc[m][n] = MFMA16(af[m], bf[n], acc[m][n]);                            \
        __syncthreads();                                                                \
    }

// QKV projection GEMM: N=3072 (q|k|v), scatters to [B,H,S,Dh] bf16, Q scaled by 1/8
__global__ __launch_bounds__(256) void k_gemm_qkv(
    const unsigned short* __restrict__ A, const unsigned short* __restrict__ Bt,
    const float* __restrict__ bq, const float* __restrict__ bk, const float* __restrict__ bv,
    unsigned short* __restrict__ qo, unsigned short* __restrict__ ko,
    unsigned short* __restrict__ vo)
{
    GEMM_BODY(A, Bt)
    const int p = col0 >> 10;  // 0=q 1=k 2=v, uniform per block
    const float* bias = (p == 0) ? bq : ((p == 1) ? bk : bv);
    unsigned short* dst = (p == 0) ? qo : ((p == 1) ? ko : vo);
    const float scl = (p == 0) ? 0.125f : 1.0f;
    #pragma unroll
    for (int m = 0; m < 4; ++m) {
        #pragma unroll
        for (int n = 0; n < 4; ++n) {
            int gcol = col0 + wc * 64 + n * 16 + frow;
            int hn = gcol & 1023;
            int h = hn >> 6, d = hn & 63;
            #pragma unroll
            for (int i = 0; i < 4; ++i) {
                int grow = row0 + wr * 64 + m * 16 + (lane >> 4) * 4 + i;
                int b = grow >> 11, s = grow & 2047;
                float v = (acc[m][n][i] + bias[hn]) * scl;
                dst[((size_t)(b * NH + h) * SEQ + s) * DH + d] = f2bf(v);
            }
        }
    }
}

// Output projection GEMM: fp32 out + bias
__global__ __launch_bounds__(256) void k_gemm_out(
    const unsigned short* __restrict__ A, const unsigned short* __restrict__ Bt,
    const float* __restrict__ bo, float* __restrict__ out)
{
    GEMM_BODY(A, Bt)
    #pragma unroll
    for (int m = 0; m < 4; ++m) {
        #pragma unroll
        for (int n = 0; n < 4; ++n) {
            int gcol = col0 + wc * 64 + n * 16 + frow;
            #pragma unroll
            for (int i = 0; i < 4; ++i) {
                int grow = row0 + wr * 64 + m * 16 + (lane >> 4) * 4 + i;
                out[(size_t)grow * DMODEL + gcol] = acc[m][n][i] + bo[gcol];
            }
        }
    }
}

// ---------- causal flash attention: LDS-staged, double-buffered, counted vmcnt ----------
// Q,K: [B*H][S][DH] bf16 (Q pre-scaled). VT: [B*H][DH][S] bf16. O: [B][S][H*DH] bf16.
// K/V^T staged via global_load_lds with pre-swizzled source; DPP rotate-reduce softmax;
// setprio around MFMA clusters. Block handles q-tile pair {31-p, p} (causal balance).
__global__ __launch_bounds__(256) void k_attn(
    const unsigned short* __restrict__ Q, const unsigned short* __restrict__ K,
    const unsigned short* __restrict__ VT, unsigned short* __restrict__ O)
{
    __shared__ __align__(16) unsigned short Ks[2][64 * 64];
    __shared__ __align__(16) unsigned short Vs[2][64 * 64];
    __shared__ __align__(16) unsigned short Ps[4][16 * 72];
    const int tid = threadIdx.x, lane = tid & 63, wave = tid >> 6;
    // XCD swizzle: 64 consecutive logical blocks (4 heads) per XCD -> 2MB KV in 4MB L2
    const int p = blockIdx.x;
    const int L = ((p & 7) << 6) | (p >> 3);
    const int bh = L >> 4, pr = L & 15;
    const unsigned short* Qb = Q + (size_t)bh * SEQ * DH;
    const unsigned short* Kb = K + (size_t)bh * SEQ * DH;
    const unsigned short* Vb = VT + (size_t)bh * SEQ * DH;  // [64][2048]
    const int frow = lane & 15, fk = (lane >> 4) * 8;
    const int srow = lane >> 3;
    const int scol = ((lane & 7) ^ srow) << 3;  // inverse-swizzled source col (elements)
    const int bb = bh >> 4, hh = bh & 15;

    for (int rep = 0; rep < 2; ++rep) {
        const int qt = rep ? pr : 31 - pr;  // long tile first
        const int q0 = qt * 64;
        short8 qf[2];
        #pragma unroll
        for (int t = 0; t < 2; ++t)
            qf[t] = *(const short8*)&Qb[(size_t)(q0 + wave * 16 + frow) * DH + t * 32 + fk];
        f32x4 oacc[4] = {};
        float mrow[4], lrow[4];
        #pragma unroll
        for (int i = 0; i < 4; ++i) { mrow[i] = -INFINITY; lrow[i] = 0.f; }

        auto stage = [&](int b, int kv0) {  // 4 gload_lds per thread
            #pragma unroll
            for (int rd = 0; rd < 2; ++rd) {
                int row = rd * 32 + wave * 8 + srow;
                gload_lds16(Kb + (size_t)(kv0 + row) * DH + scol,
                            &Ks[b][(rd * 32 + wave * 8) * 64]);
                gload_lds16(Vb + (size_t)row * SEQ + kv0 + scol,
                            &Vs[b][(rd * 32 + wave * 8) * 64]);
            }
        };

        auto compute = [&](int cb_, bool diag) {
            const char* kbase = (const char*)&Ks[cb_][0];
            const char* vbase = (const char*)&Vs[cb_][0];
            const int sw = (frow & 7) << 4;
            // QK^T from swizzled LDS
            f32x4 sc[4];
            __builtin_amdgcn_s_setprio(1);
            #pragma unroll
            for (int n = 0; n < 4; ++n) {
                f32x4 s = {0.f, 0.f, 0.f, 0.f};
                #pragma unroll
                for (int t = 0; t < 2; ++t) {
                    int cbt = (t * 32 + fk) * 2;
                    short8 kb = *(const short8*)(kbase + (n * 16 + frow) * 128 + (cbt ^ sw));
                    s = MFMA16(qf[t], kb, s);
                }
                sc[n] = s;
            }
            __builtin_amdgcn_s_setprio(0);
            if (diag) {  // causal mask on diagonal tile
                #pragma unroll
                for (int n = 0; n < 4; ++n) {
                    int col = n * 16 + frow;
                    #pragma unroll
                    for (int i = 0; i < 4; ++i) {
                        int qrel = wave * 16 + (lane >> 4) * 4 + i;
                        if (col > qrel) sc[n][i] = -INFINITY;
                    }
                }
            }
            // online softmax, DPP rotate-reduce over the 16-lane row group, defer-max THR=8
            float mx[4];
            #pragma unroll
            for (int i = 0; i < 4; ++i)
                mx[i] = dpp16_max(fmaxf(fmaxf(sc[0][i], sc[1][i]), fmaxf(sc[2][i], sc[3][i])));
            float dm = fmaxf(fmaxf(mx[0] - mrow[0], mx[1] - mrow[1]),
                             fmaxf(mx[2] - mrow[2], mx[3] - mrow[3]));
            if (__any(dm > 8.f)) {
                #pragma unroll
                for (int i = 0; i < 4; ++i) {
                    float mnew = fmaxf(mrow[i], mx[i]);
                    float scl = __expf(mrow[i] - mnew);
                    mrow[i] = mnew;
                    lrow[i] *= scl;
                    #pragma unroll
                    for (int n = 0; n < 4; ++n) oacc[n][i] *= scl;
                }
            }
            #pragma unroll
            for (int i = 0; i < 4; ++i) {
                float rsum = 0.f;
                #pragma unroll
                for (int n = 0; n < 4; ++n) {
                    float pv = __expf(sc[n][i] - mrow[i]);
                    sc[n][i] = pv;
                    rsum += pv;
                }
                lrow[i] += dpp16_sum(rsum);
            }
            // P -> wave-private LDS (stride 72, 2-way free)
            #pragma unroll
            for (int n = 0; n < 4; ++n)
                #pragma unroll
                for (int i = 0; i < 4; ++i)
                    Ps[wave][((lane >> 4) * 4 + i) * 72 + n * 16 + frow] = f2bf(sc[n][i]);
            asm volatile("s_waitcnt lgkmcnt(0)" ::: "memory");
            short8 pa[2];
            #pragma unroll
            for (int t = 0; t < 2; ++t)
                pa[t] = *(const short8*)&Ps[wave][frow * 72 + t * 32 + fk];
            // PV from swizzled LDS V^T
            __builtin_amdgcn_s_setprio(1);
            #pragma unroll
            for (int n = 0; n < 4; ++n)
                #pragma unroll
                for (int t = 0; t < 2; ++t) {
                    int cbt = (t * 32 + fk) * 2;
                    short8 vb2 = *(const short8*)(vbase + (n * 16 + frow) * 128 + (cbt ^ sw));
                    oacc[n] = MFMA16(pa[t], vb2, oacc[n]);
                }
            __builtin_amdgcn_s_setprio(0);
        };

        // pipelined K-loop: stage(kt+1) in flight across barrier, vmcnt(4) not 0
        stage(0, 0);
        int cur = 0;
        for (int kt = 0; kt < qt; ++kt) {
            stage(cur ^ 1, (kt + 1) * 64);
            asm volatile("s_waitcnt vmcnt(4)" ::: "memory");
            __builtin_amdgcn_s_barrier();
            compute(cur, false);
            __builtin_amdgcn_s_barrier();
            cur ^= 1;
        }
        asm volatile("s_waitcnt vmcnt(0)" ::: "memory");
        __builtin_amdgcn_s_barrier();
        compute(cur, true);
        // epilogue: O[b][s][h*64+d], normalized
        #pragma unroll
        for (int n = 0; n < 4; ++n) {
            #pragma unroll
            for (int i = 0; i < 4; ++i) {
                int qrow = q0 + wave * 16 + (lane >> 4) * 4 + i;
                float v = oacc[n][i] / lrow[i];
                O[((size_t)(bb * SEQ + qrow)) * DMODEL + hh * DH + n * 16 + frow] = f2bf(v);
            }
        }
        __builtin_amdgcn_s_barrier();  // all waves done reading bufs before next rep's stage
    }
}

extern "C" void kernel_launch(void* const* d_in, const int* in_sizes, int n_in,
                              void* d_out, int out_size, void* d_ws, size_t ws_size,
                              hipStream_t stream) {
    const float* x  = (const float*)d_in[0];
    const float* wq = (const float*)d_in[1];
    const float* bq = (const float*)d_in[2];
    const float* wk = (const float*)d_in[3];
    const float* bk = (const float*)d_in[4];
    const float* wv = (const float*)d_in[5];
    const float* bv = (const float*)d_in[6];
    const float* wo = (const float*)d_in[7];
    const float* bo = (const float*)d_in[8];
    float* out = (float*)d_out;

    char* w = (char*)d_ws;
    unsigned short* xb    = (unsigned short*)(w);            // 8 MB, freed after qkv GEMM
    unsigned short* vT    = (unsigned short*)(w);            // reuses xb region
    unsigned short* wqkvT = (unsigned short*)(w + 8388608);
    unsigned short* woT   = (unsigned short*)(w + 14680064);
    unsigned short* qarr  = (unsigned short*)(w + 16777216);
    unsigned short* karr  = (unsigned short*)(w + 25165824);
    unsigned short* varr  = (unsigned short*)(w + 33554432);
    unsigned short* attnb = (unsigned short*)(w + 41943040);

    k_cvt<<<2048, 256, 0, stream>>>(x, xb);
    k_transpose_w4<<<dim3(32, 32, 4), dim3(32, 8), 0, stream>>>(wq, wk, wv, wo, wqkvT, woT);
    k_gemm_qkv<<<dim3(24, 32), 256, 0, stream>>>(xb, wqkvT, bq, bk, bv, qarr, karr, varr);
    k_transpose_v<<<dim3(32, 32), 256, 0, stream>>>(varr, vT);
    k_attn<<<dim3(512), 256, 0, stream>>>(qarr, karr, vT, attnb);
    k_gemm_out<<<dim3(8, 32), 256, 0, stream>>>(attnb, woT, bo, out);
}

// Round 9
// 207.514 us; speedup vs baseline: 1.8828x; 1.0193x over previous
//
#include <hip/hip_runtime.h>
#include <hip/hip_bf16.h>
#include <stdint.h>

#define NH 16
#define DH 64
#define BATCH 2
#define SEQ 2048
#define DMODEL 1024

typedef __attribute__((ext_vector_type(8))) short short8;
typedef __attribute__((ext_vector_type(4))) float f32x4;

#define MFMA16(a, b, c) __builtin_amdgcn_mfma_f32_16x16x32_bf16(a, b, c, 0, 0, 0)

__device__ inline unsigned short f2bf(float f) {
    union { float f; unsigned u; } v; v.f = f;
    unsigned r = v.u + 0x7fff + ((v.u >> 16) & 1);
    return (unsigned short)(r >> 16);
}

__device__ inline void gload_lds16(const unsigned short* g, unsigned short* l) {
    __builtin_amdgcn_global_load_lds((const __attribute__((address_space(1))) void*)g,
                                     (__attribute__((address_space(3))) void*)l, 16, 0, 0);
}

// 16-lane rotate-reduce via DPP row_ror (VALU-speed). Group = one DPP row of 16.
__device__ inline float dpp16_max(float v) {
    int t;
    t = __builtin_amdgcn_mov_dpp(__float_as_int(v), 0x121, 0xf, 0xf, false);
    v = fmaxf(v, __int_as_float(t));
    t = __builtin_amdgcn_mov_dpp(__float_as_int(v), 0x122, 0xf, 0xf, false);
    v = fmaxf(v, __int_as_float(t));
    t = __builtin_amdgcn_mov_dpp(__float_as_int(v), 0x124, 0xf, 0xf, false);
    v = fmaxf(v, __int_as_float(t));
    t = __builtin_amdgcn_mov_dpp(__float_as_int(v), 0x128, 0xf, 0xf, false);
    v = fmaxf(v, __int_as_float(t));
    return v;
}
__device__ inline float dpp16_sum(float v) {
    int t;
    t = __builtin_amdgcn_mov_dpp(__float_as_int(v), 0x121, 0xf, 0xf, false);
    v += __int_as_float(t);
    t = __builtin_amdgcn_mov_dpp(__float_as_int(v), 0x122, 0xf, 0xf, false);
    v += __int_as_float(t);
    t = __builtin_amdgcn_mov_dpp(__float_as_int(v), 0x124, 0xf, 0xf, false);
    v += __int_as_float(t);
    t = __builtin_amdgcn_mov_dpp(__float_as_int(v), 0x128, 0xf, 0xf, false);
    v += __int_as_float(t);
    return v;
}

// ---------- fp32 -> bf16 convert (8 elems/thread) ----------
__global__ void k_cvt(const float* __restrict__ in, unsigned short* __restrict__ out) {
    size_t i = ((size_t)blockIdx.x * 256 + threadIdx.x) * 8;
    f32x4 a = *(const f32x4*)(in + i);
    f32x4 b = *(const f32x4*)(in + i + 4);
    short8 o;
    o[0] = (short)f2bf(a[0]); o[1] = (short)f2bf(a[1]);
    o[2] = (short)f2bf(a[2]); o[3] = (short)f2bf(a[3]);
    o[4] = (short)f2bf(b[0]); o[5] = (short)f2bf(b[1]);
    o[6] = (short)f2bf(b[2]); o[7] = (short)f2bf(b[3]);
    *(short8*)(out + i) = o;
}

// ---------- fused weight transpose x4: [K][N] fp32 -> [N][K] bf16 ----------
__global__ void k_transpose_w4(const float* __restrict__ wq, const float* __restrict__ wk,
                               const float* __restrict__ wv, const float* __restrict__ wo,
                               unsigned short* __restrict__ qkvT, unsigned short* __restrict__ oT) {
    __shared__ float tile[32][33];
    const int z = blockIdx.z;
    const float* w = (z == 0) ? wq : (z == 1) ? wk : (z == 2) ? wv : wo;
    unsigned short* out = (z == 3) ? oT : qkvT + (size_t)z * 1024 * 1024;
    int k0 = blockIdx.x * 32, n0 = blockIdx.y * 32;
    int tx = threadIdx.x, ty = threadIdx.y;  // 32 x 8
    #pragma unroll
    for (int j = 0; j < 32; j += 8)
        tile[ty + j][tx] = w[(size_t)(k0 + ty + j) * DMODEL + n0 + tx];
    __syncthreads();
    #pragma unroll
    for (int j = 0; j < 32; j += 8)
        out[(size_t)(n0 + ty + j) * DMODEL + k0 + tx] = f2bf(tile[tx][ty + j]);
}

// ---------- V transpose per head: [bh][2048][64] -> [bh][64][2048] bf16 ----------
__global__ __launch_bounds__(256) void k_transpose_v(const unsigned short* __restrict__ v,
                                                     unsigned short* __restrict__ vt) {
    __shared__ __align__(16) unsigned short tile[64][72];
    int bh = blockIdx.y, st = blockIdx.x;
    const unsigned short* src = v + ((size_t)bh * SEQ + st * 64) * DH;
    int r = threadIdx.x >> 2, c = (threadIdx.x & 3) * 16;
    *(short8*)&tile[r][c]     = *(const short8*)&src[r * DH + c];
    *(short8*)&tile[r][c + 8] = *(const short8*)&src[r * DH + c + 8];
    __syncthreads();
    int d = r, sb = c;
    short8 o0, o1;
    #pragma unroll
    for (int j = 0; j < 8; ++j) { o0[j] = (short)tile[sb + j][d]; o1[j] = (short)tile[sb + 8 + j][d]; }
    unsigned short* dst = vt + ((size_t)bh * DH + d) * SEQ + st * 64 + sb;
    *(short8*)dst = o0;
    *(short8*)(dst + 8) = o1;
}

// ---------- GEMM core: 128x128 tile, BK=32, 4 waves (2x2), m97 structure ----------
// Bijective XCD swizzle on the flat tile id (nwg % 8 == 0 for all our grids).
#define GEMM_BODY(A_, Bt_)                                                              \
    __shared__ __align__(16) unsigned short As[128 * 32];                               \
    __shared__ __align__(16) unsigned short Bs[128 * 32];                               \
    const int tid = threadIdx.x;                                                        \
    const int lane = tid & 63, wave = tid >> 6;                                         \
    const int wr = wave >> 1, wc = wave & 1;                                            \
    const int nwgx = gridDim.x;                                                         \
    const int flat = blockIdx.y * nwgx + blockIdx.x;                                    \
    const int qq = (nwgx * gridDim.y) >> 3;                                             \
    const int newid = (flat & 7) * qq + (flat >> 3);                                    \
    const int row0 = (newid / nwgx) * 128, col0 = (newid % nwgx) * 128;                 \
    const int frow = lane & 15, fk = (lane >> 4) * 8;                                   \
    f32x4 acc[4][4] = {};                                                               \
    const int lr = tid >> 2;                                                            \
    const int lc = (tid & 3) * 8;                                                       \
    const unsigned short* ga0 = A_ + (size_t)(row0 + lr) * 1024 + lc;                   \
    const unsigned short* gb0 = Bt_ + (size_t)(col0 + lr) * 1024 + lc;                  \
    for (int kt = 0; kt < 1024; kt += 32) {                                             \
        gload_lds16(ga0 + kt, As + wave * 512);                                         \
        gload_lds16(ga0 + 64 * 1024 + kt, As + 2048 + wave * 512);                      \
        gload_lds16(gb0 + kt, Bs + wave * 512);                                         \
        gload_lds16(gb0 + 64 * 1024 + kt, Bs + 2048 + wave * 512);                      \
        __syncthreads();                                                                \
        short8 af[4], bf[4];                                                            \
        _Pragma("unroll")                                                               \
        for (int m = 0; m < 4; ++m)                                                     \
            af[m] = *(const short8*)&As[(wr * 64 + m * 16 + frow) * 32 + fk];           \
        _Pragma("unroll")                                                               \
        for (int n = 0; n < 4; ++n)                                                     \
            bf[n] = *(const short8*)&Bs[(wc * 64 + n * 16 + frow) * 32 + fk];           \
        _Pragma("unroll")                                                               \
        for (int m = 0; m < 4; ++m)                                                     \
            _Pragma("unroll")                                                           \
            for (int n = 0; n < 4; ++n)                                                 \
                acc[m][n] = MFMA16(af[m], bf[n], acc[m][n]);                            \
        __syncthreads();                                                                \
    }

// QKV projection GEMM: N=3072 (q|k|v), scatters to [B,H,S,Dh] bf16, Q scaled by 1/8
__global__ __launch_bounds__(256) void k_gemm_qkv(
    const unsigned short* __restrict__ A, const unsigned short* __restrict__ Bt,
    const float* __restrict__ bq, const float* __restrict__ bk, const float* __restrict__ bv,
    unsigned short* __restrict__ qo, unsigned short* __restrict__ ko,
    unsigned short* __restrict__ vo)
{
    GEMM_BODY(A, Bt)
    const int p = col0 >> 10;  // 0=q 1=k 2=v, uniform per block
    const float* bias = (p == 0) ? bq : ((p == 1) ? bk : bv);
    unsigned short* dst = (p == 0) ? qo : ((p == 1) ? ko : vo);
    const float scl = (p == 0) ? 0.125f : 1.0f;
    #pragma unroll
    for (int m = 0; m < 4; ++m) {
        #pragma unroll
        for (int n = 0; n < 4; ++n) {
            int gcol = col0 + wc * 64 + n * 16 + frow;
            int hn = gcol & 1023;
            int h = hn >> 6, d = hn & 63;
            #pragma unroll
            for (int i = 0; i < 4; ++i) {
                int grow = row0 + wr * 64 + m * 16 + (lane >> 4) * 4 + i;
                int b = grow >> 11, s = grow & 2047;
                float v = (acc[m][n][i] + bias[hn]) * scl;
                dst[((size_t)(b * NH + h) * SEQ + s) * DH + d] = f2bf(v);
            }
        }
    }
}

// Output projection GEMM: fp32 out + bias
__global__ __launch_bounds__(256) void k_gemm_out(
    const unsigned short* __restrict__ A, const unsigned short* __restrict__ Bt,
    const float* __restrict__ bo, float* __restrict__ out)
{
    GEMM_BODY(A, Bt)
    #pragma unroll
    for (int m = 0; m < 4; ++m) {
        #pragma unroll
        for (int n = 0; n < 4; ++n) {
            int gcol = col0 + wc * 64 + n * 16 + frow;
            #pragma unroll
            for (int i = 0; i < 4; ++i) {
                int grow = row0 + wr * 64 + m * 16 + (lane >> 4) * 4 + i;
                out[(size_t)grow * DMODEL + gcol] = acc[m][n][i] + bo[gcol];
            }
        }
    }
}

// ---------- causal flash attention: LDS-staged, double-buffered, counted vmcnt ----------
// Q,K: [B*H][S][DH] bf16 (Q pre-scaled). VT: [B*H][DH][S] bf16. O: [B][S][H*DH] bf16.
// DPP softmax, per-lane deferred l-sum (reduced once in epilogue), f2bf P-store,
// setprio on MFMA clusters. Block handles q-tile pair {31-p, p} (causal balance).
__global__ __launch_bounds__(256) void k_attn(
    const unsigned short* __restrict__ Q, const unsigned short* __restrict__ K,
    const unsigned short* __restrict__ VT, unsigned short* __restrict__ O)
{
    __shared__ __align__(16) unsigned short Ks[2][64 * 64];
    __shared__ __align__(16) unsigned short Vs[2][64 * 64];
    __shared__ __align__(16) unsigned short Ps[4][16 * 72];
    const int tid = threadIdx.x, lane = tid & 63, wave = tid >> 6;
    // XCD swizzle: 64 consecutive logical blocks (4 heads) per XCD -> 2MB KV in 4MB L2
    const int p = blockIdx.x;
    const int L = ((p & 7) << 6) | (p >> 3);
    const int bh = L >> 4, pr = L & 15;
    const unsigned short* Qb = Q + (size_t)bh * SEQ * DH;
    const unsigned short* Kb = K + (size_t)bh * SEQ * DH;
    const unsigned short* Vb = VT + (size_t)bh * SEQ * DH;  // [64][2048]
    const int frow = lane & 15, fk = (lane >> 4) * 8;
    const int srow = lane >> 3;
    const int scol = ((lane & 7) ^ srow) << 3;  // inverse-swizzled source col (elements)
    const int bb = bh >> 4, hh = bh & 15;

    for (int rep = 0; rep < 2; ++rep) {
        const int qt = rep ? pr : 31 - pr;  // long tile first
        const int q0 = qt * 64;
        short8 qf[2];
        #pragma unroll
        for (int t = 0; t < 2; ++t)
            qf[t] = *(const short8*)&Qb[(size_t)(q0 + wave * 16 + frow) * DH + t * 32 + fk];
        f32x4 oacc[4] = {};
        float mrow[4], lrow[4];
        #pragma unroll
        for (int i = 0; i < 4; ++i) { mrow[i] = -INFINITY; lrow[i] = 0.f; }

        auto stage = [&](int b, int kv0) {  // 4 gload_lds per thread
            #pragma unroll
            for (int rd = 0; rd < 2; ++rd) {
                int row = rd * 32 + wave * 8 + srow;
                gload_lds16(Kb + (size_t)(kv0 + row) * DH + scol,
                            &Ks[b][(rd * 32 + wave * 8) * 64]);
                gload_lds16(Vb + (size_t)row * SEQ + kv0 + scol,
                            &Vs[b][(rd * 32 + wave * 8) * 64]);
            }
        };

        auto compute = [&](int cb_, bool diag) {
            const char* kbase = (const char*)&Ks[cb_][0];
            const char* vbase = (const char*)&Vs[cb_][0];
            const int sw = (frow & 7) << 4;
            // QK^T from swizzled LDS
            f32x4 sc[4];
            __builtin_amdgcn_s_setprio(1);
            #pragma unroll
            for (int n = 0; n < 4; ++n) {
                f32x4 s = {0.f, 0.f, 0.f, 0.f};
                #pragma unroll
                for (int t = 0; t < 2; ++t) {
                    int cbt = (t * 32 + fk) * 2;
                    short8 kb = *(const short8*)(kbase + (n * 16 + frow) * 128 + (cbt ^ sw));
                    s = MFMA16(qf[t], kb, s);
                }
                sc[n] = s;
            }
            __builtin_amdgcn_s_setprio(0);
            if (diag) {  // causal mask on diagonal tile
                #pragma unroll
                for (int n = 0; n < 4; ++n) {
                    int col = n * 16 + frow;
                    #pragma unroll
                    for (int i = 0; i < 4; ++i) {
                        int qrel = wave * 16 + (lane >> 4) * 4 + i;
                        if (col > qrel) sc[n][i] = -INFINITY;
                    }
                }
            }
            // online softmax, DPP rotate-reduce max, defer-max THR=8, per-lane l partials
            float mx[4];
            #pragma unroll
            for (int i = 0; i < 4; ++i)
                mx[i] = dpp16_max(fmaxf(fmaxf(sc[0][i], sc[1][i]), fmaxf(sc[2][i], sc[3][i])));
            float dm = fmaxf(fmaxf(mx[0] - mrow[0], mx[1] - mrow[1]),
                             fmaxf(mx[2] - mrow[2], mx[3] - mrow[3]));
            if (__any(dm > 8.f)) {
                #pragma unroll
                for (int i = 0; i < 4; ++i) {
                    float mnew = fmaxf(mrow[i], mx[i]);
                    float scl = __expf(mrow[i] - mnew);
                    mrow[i] = mnew;
                    lrow[i] *= scl;
                    #pragma unroll
                    for (int n = 0; n < 4; ++n) oacc[n][i] *= scl;
                }
            }
            #pragma unroll
            for (int i = 0; i < 4; ++i) {
                float rsum = 0.f;
                #pragma unroll
                for (int n = 0; n < 4; ++n) {
                    float pv = __expf(sc[n][i] - mrow[i]);
                    sc[n][i] = pv;
                    rsum += pv;
                }
                lrow[i] += rsum;  // cross-lane sum deferred to epilogue
            }
            // P -> wave-private LDS (stride 72, 2-way free), verified f2bf path
            #pragma unroll
            for (int n = 0; n < 4; ++n)
                #pragma unroll
                for (int i = 0; i < 4; ++i)
                    Ps[wave][((lane >> 4) * 4 + i) * 72 + n * 16 + frow] = f2bf(sc[n][i]);
            asm volatile("s_waitcnt lgkmcnt(0)" ::: "memory");
            short8 pa[2];
            #pragma unroll
            for (int t = 0; t < 2; ++t)
                pa[t] = *(const short8*)&Ps[wave][frow * 72 + t * 32 + fk];
            // PV from swizzled LDS V^T
            __builtin_amdgcn_s_setprio(1);
            #pragma unroll
            for (int n = 0; n < 4; ++n)
                #pragma unroll
                for (int t = 0; t < 2; ++t) {
                    int cbt = (t * 32 + fk) * 2;
                    short8 vb2 = *(const short8*)(vbase + (n * 16 + frow) * 128 + (cbt ^ sw));
                    oacc[n] = MFMA16(pa[t], vb2, oacc[n]);
                }
            __builtin_amdgcn_s_setprio(0);
        };

        // pipelined K-loop: stage(kt+1) in flight across barrier, vmcnt(4) not 0
        stage(0, 0);
        int cur = 0;
        for (int kt = 0; kt < qt; ++kt) {
            stage(cur ^ 1, (kt + 1) * 64);
            asm volatile("s_waitcnt vmcnt(4)" ::: "memory");
            __builtin_amdgcn_s_barrier();
            compute(cur, false);
            __builtin_amdgcn_s_barrier();
            cur ^= 1;
        }
        asm volatile("s_waitcnt vmcnt(0)" ::: "memory");
        __builtin_amdgcn_s_barrier();
        compute(cur, true);
        // epilogue: finish deferred l reduction, normalize, store
        float lt[4];
        #pragma unroll
        for (int i = 0; i < 4; ++i) lt[i] = dpp16_sum(lrow[i]);
        #pragma unroll
        for (int n = 0; n < 4; ++n) {
            #pragma unroll
            for (int i = 0; i < 4; ++i) {
                int qrow = q0 + wave * 16 + (lane >> 4) * 4 + i;
                float v = oacc[n][i] / lt[i];
                O[((size_t)(bb * SEQ + qrow)) * DMODEL + hh * DH + n * 16 + frow] = f2bf(v);
            }
        }
        __builtin_amdgcn_s_barrier();  // all waves done reading bufs before next rep's stage
    }
}

extern "C" void kernel_launch(void* const* d_in, const int* in_sizes, int n_in,
                              void* d_out, int out_size, void* d_ws, size_t ws_size,
                              hipStream_t stream) {
    const float* x  = (const float*)d_in[0];
    const float* wq = (const float*)d_in[1];
    const float* bq = (const float*)d_in[2];
    const float* wk = (const float*)d_in[3];
    const float* bk = (const float*)d_in[4];
    const float* wv = (const float*)d_in[5];
    const float* bv = (const float*)d_in[6];
    const float* wo = (const float*)d_in[7];
    const float* bo = (const float*)d_in[8];
    float* out = (float*)d_out;

    char* w = (char*)d_ws;
    unsigned short* xb    = (unsigned short*)(w);            // 8 MB, freed after qkv GEMM
    unsigned short* vT    = (unsigned short*)(w);            // reuses xb region
    unsigned short* wqkvT = (unsigned short*)(w + 8388608);
    unsigned short* woT   = (unsigned short*)(w + 14680064);
    unsigned short* qarr  = (unsigned short*)(w + 16777216);
    unsigned short* karr  = (unsigned short*)(w + 25165824);
    unsigned short* varr  = (unsigned short*)(w + 33554432);
    unsigned short* attnb = (unsigned short*)(w + 41943040);

    k_cvt<<<2048, 256, 0, stream>>>(x, xb);
    k_transpose_w4<<<dim3(32, 32, 4), dim3(32, 8), 0, stream>>>(wq, wk, wv, wo, wqkvT, woT);
    k_gemm_qkv<<<dim3(24, 32), 256, 0, stream>>>(xb, wqkvT, bq, bk, bv, qarr, karr, varr);
    k_transpose_v<<<dim3(32, 32), 256, 0, stream>>>(varr, vT);
    k_attn<<<dim3(512), 256, 0, stream>>>(qarr, karr, vT, attnb);
    k_gemm_out<<<dim3(8, 32), 256, 0, stream>>>(attnb, woT, bo, out);
}